// Round 1
// baseline (292.222 us; speedup 1.0000x reference)
//
#include <hip/hip_runtime.h>
#include <hip/hip_fp16.h>

// Problem constants (B=4, S=8192, IN=OUT=1024, GROUP=128)
#define K_DIM 1024
#define N_DIM 1024

typedef int v4i __attribute__((ext_vector_type(4)));

__device__ __forceinline__ void async_load16(const void* g, void* l) {
    __builtin_amdgcn_global_load_lds(
        (const __attribute__((address_space(1))) unsigned int*)g,
        (__attribute__((address_space(3))) unsigned int*)l,
        16, 0, 0);
}

// ---------------- Kernel A: weight prep ----------------
// One wave per weight row (1024 elems). Lane l holds elements [l*16, l*16+16).
// Group g (128 elems) = lanes 8g..8g+7. Produces:
//   wq[row][k]    = sign(w) in {+1,-1} int8
//   wscale[row]   = mean over 8 groups of fp32(fp16(max(absmax,1e-8)))
__global__ __launch_bounds__(256) void prep_w(const float* __restrict__ w,
                                              signed char* __restrict__ wq,
                                              float* __restrict__ wscale) {
    const int lane = threadIdx.x & 63;
    const int row  = blockIdx.x * 4 + (threadIdx.x >> 6);
    const float4* wr = (const float4*)(w + (size_t)row * K_DIM);
    float4 v[4];
#pragma unroll
    for (int j = 0; j < 4; ++j) v[j] = wr[lane * 4 + j];  // 16 consecutive floats

    float g = 0.f;
#pragma unroll
    for (int j = 0; j < 4; ++j) {
        g = fmaxf(g, fabsf(v[j].x)); g = fmaxf(g, fabsf(v[j].y));
        g = fmaxf(g, fabsf(v[j].z)); g = fmaxf(g, fabsf(v[j].w));
    }
    // reduce absmax within 8-lane groups (one group = 128 elements)
    g = fmaxf(g, __shfl_xor(g, 1, 64));
    g = fmaxf(g, __shfl_xor(g, 2, 64));
    g = fmaxf(g, __shfl_xor(g, 4, 64));
    const float s = __half2float(__float2half(fmaxf(g, 1e-8f)));  // fp16 storage round-trip
    // sum one value per group across the 8 groups (s is uniform within a group)
    float t = s;
    t += __shfl_xor(t, 8, 64);
    t += __shfl_xor(t, 16, 64);
    t += __shfl_xor(t, 32, 64);
    if (lane == 0) wscale[row] = t * 0.125f;  // mean over 8 groups

    int pk[4];
#pragma unroll
    for (int j = 0; j < 4; ++j) {
        const int b0 = (v[j].x > 0.f) ? 1 : -1;
        const int b1 = (v[j].y > 0.f) ? 1 : -1;
        const int b2 = (v[j].z > 0.f) ? 1 : -1;
        const int b3 = (v[j].w > 0.f) ? 1 : -1;
        pk[j] = (b0 & 255) | ((b1 & 255) << 8) | ((b2 & 255) << 16) | (b3 << 24);
    }
    *(int4*)(wq + (size_t)row * K_DIM + lane * 16) = make_int4(pk[0], pk[1], pk[2], pk[3]);
}

// ---------------- Kernel B: per-token activation quant ----------------
// One wave per token row. Coalesced float4 loads (lane-stride 16B), full-wave
// shuffle absmax, RNE rounding (rintf == jnp.round), packed int8 dword stores.
__global__ __launch_bounds__(256) void quant_x(const float* __restrict__ x,
                                               signed char* __restrict__ xq,
                                               float* __restrict__ xs) {
    const int lane = threadIdx.x & 63;
    const int row  = blockIdx.x * 4 + (threadIdx.x >> 6);
    const float4* xr = (const float4*)(x + (size_t)row * K_DIM);
    float4 v[4];
#pragma unroll
    for (int j = 0; j < 4; ++j) v[j] = xr[lane + 64 * j];

    float am = 0.f;
#pragma unroll
    for (int j = 0; j < 4; ++j) {
        am = fmaxf(am, fabsf(v[j].x)); am = fmaxf(am, fabsf(v[j].y));
        am = fmaxf(am, fabsf(v[j].z)); am = fmaxf(am, fabsf(v[j].w));
    }
#pragma unroll
    for (int off = 32; off >= 1; off >>= 1) am = fmaxf(am, __shfl_xor(am, off, 64));
    const float scale = fmaxf(am, 1e-8f) / 127.f;

    int* xqi = (int*)(xq + (size_t)row * K_DIM);
#pragma unroll
    for (int j = 0; j < 4; ++j) {
        const int b0 = (int)fminf(fmaxf(rintf(v[j].x / scale), -128.f), 127.f);
        const int b1 = (int)fminf(fmaxf(rintf(v[j].y / scale), -128.f), 127.f);
        const int b2 = (int)fminf(fmaxf(rintf(v[j].z / scale), -128.f), 127.f);
        const int b3 = (int)fminf(fmaxf(rintf(v[j].w / scale), -128.f), 127.f);
        xqi[lane + 64 * j] = (b0 & 255) | ((b1 & 255) << 8) | ((b2 & 255) << 16) | (b3 << 24);
    }
    if (lane == 0) xs[row] = scale;
}

// ---------------- Kernel C: int8 GEMM (m97 structure, i8 port) ----------------
// C[m][n] = sum_k A[m][k] * Bw[n][k]; A = xq [M,1024], Bw = wq [1024,1024] (B^T form).
// 128x128 tile, BK=128 bytes/stage, 256 threads = 4 waves in 2x2, each wave
// 4x4 tiles of 16x16 via mfma_i32_16x16x64_i8 (2 K-steps per stage).
__global__ __launch_bounds__(256) void gemm_i8(const signed char* __restrict__ A,
                                               const signed char* __restrict__ Bw,
                                               const float* __restrict__ xs,
                                               const float* __restrict__ wscale,
                                               const float* __restrict__ bias,
                                               float* __restrict__ out) {
    __shared__ __align__(16) signed char As[128 * 128];
    __shared__ __align__(16) signed char Bs[128 * 128];

    const int tid  = threadIdx.x;
    const int lane = tid & 63;
    const int wave = tid >> 6;
    const int wm = wave >> 1;   // 0..1
    const int wn = wave & 1;    // 0..1

    const int bid   = blockIdx.x;
    const int nT    = bid & 7;          // 8 n-tiles (N=1024)
    const size_t mBase = (size_t)(bid >> 3) * 128;
    const int nBase = nT * 128;

    v4i acc[4][4] = {};

    // staging: per call, 256 threads x 16B = 4KB = 32 rows of 128B
    const int srow = tid >> 3;          // 0..31
    const int scol = (tid & 7) * 16;    // byte col within BK
    const signed char* Ag = A  + (mBase + srow) * K_DIM + scol;
    const signed char* Bg = Bw + (size_t)(nBase + srow) * K_DIM + scol;

    for (int kt = 0; kt < 8; ++kt) {
        const int koff = kt * 128;
#pragma unroll
        for (int c = 0; c < 4; ++c) {
            async_load16(Ag + (size_t)(c * 32) * K_DIM + koff, As + c * 4096 + tid * 16);
            async_load16(Bg + (size_t)(c * 32) * K_DIM + koff, Bs + c * 4096 + tid * 16);
        }
        __syncthreads();   // compiler emits vmcnt(0) drain before s_barrier

#pragma unroll
        for (int ks = 0; ks < 2; ++ks) {
            v4i af[4], bf[4];
#pragma unroll
            for (int mt = 0; mt < 4; ++mt)
                af[mt] = *(const v4i*)(As + (wm * 64 + mt * 16 + (lane & 15)) * 128
                                          + ks * 64 + (lane >> 4) * 16);
#pragma unroll
            for (int nt = 0; nt < 4; ++nt)
                bf[nt] = *(const v4i*)(Bs + (wn * 64 + nt * 16 + (lane & 15)) * 128
                                          + ks * 64 + (lane >> 4) * 16);
#pragma unroll
            for (int mt = 0; mt < 4; ++mt)
#pragma unroll
                for (int nt = 0; nt < 4; ++nt)
                    acc[mt][nt] = __builtin_amdgcn_mfma_i32_16x16x64_i8(
                        af[mt], bf[nt], acc[mt][nt], 0, 0, 0);
        }
        __syncthreads();
    }

    // epilogue: C/D layout col = lane&15, row = (lane>>4)*4 + reg
    const int cc = lane & 15;
    const int rq = (lane >> 4) * 4;
    float xsr[4][4];
#pragma unroll
    for (int mt = 0; mt < 4; ++mt)
#pragma unroll
        for (int i = 0; i < 4; ++i)
            xsr[mt][i] = xs[mBase + wm * 64 + mt * 16 + rq + i];

#pragma unroll
    for (int nt = 0; nt < 4; ++nt) {
        const int col  = nBase + wn * 64 + nt * 16 + cc;
        const float wsc = wscale[col];
        const float bb  = bias[col];
#pragma unroll
        for (int mt = 0; mt < 4; ++mt) {
#pragma unroll
            for (int i = 0; i < 4; ++i) {
                const size_t row = mBase + wm * 64 + mt * 16 + rq + i;
                out[row * N_DIM + col] = ((float)acc[mt][nt][i] * xsr[mt][i]) * wsc + bb;
            }
        }
    }
}

extern "C" void kernel_launch(void* const* d_in, const int* in_sizes, int n_in,
                              void* d_out, int out_size, void* d_ws, size_t ws_size,
                              hipStream_t stream) {
    const float* x    = (const float*)d_in[0];
    const float* w    = (const float*)d_in[1];
    const float* bias = (const float*)d_in[2];
    float* out = (float*)d_out;

    const int BT = in_sizes[0] / K_DIM;  // 32768 tokens

    // workspace carve (all offsets 256B-aligned)
    char* ws = (char*)d_ws;
    signed char* xq     = (signed char*)ws;                           // BT*1024 B
    float*       xs     = (float*)(ws + (size_t)BT * K_DIM);          // BT*4 B
    signed char* wq     = (signed char*)(ws + (size_t)BT * K_DIM + (size_t)BT * 4);  // 1 MB
    float*       wscale = (float*)((char*)wq + (size_t)N_DIM * K_DIM);               // 4 KB

    prep_w<<<N_DIM / 4, 256, 0, stream>>>(w, wq, wscale);
    quant_x<<<BT / 4, 256, 0, stream>>>(x, xq, xs);
    gemm_i8<<<(BT / 128) * (N_DIM / 128), 256, 0, stream>>>(xq, wq, xs, wscale, bias, out);
}

// Round 2
// 276.624 us; speedup vs baseline: 1.0564x; 1.0564x over previous
//
#include <hip/hip_runtime.h>
#include <hip/hip_fp16.h>

// Problem constants (B=4, S=8192, IN=OUT=1024, GROUP=128)
#define K_DIM 1024
#define N_DIM 1024

typedef int v4i __attribute__((ext_vector_type(4)));

__device__ __forceinline__ void async_load16(const void* g, void* l) {
    __builtin_amdgcn_global_load_lds(
        (const __attribute__((address_space(1))) unsigned int*)g,
        (__attribute__((address_space(3))) unsigned int*)l,
        16, 0, 0);
}

// ---------------- Kernel A: weight prep ----------------
// One wave per weight row (1024 elems). Lane l holds elements [l*16, l*16+16).
// Group g (128 elems) = lanes 8g..8g+7.
__global__ __launch_bounds__(256) void prep_w(const float* __restrict__ w,
                                              signed char* __restrict__ wq,
                                              float* __restrict__ wscale) {
    const int lane = threadIdx.x & 63;
    const int row  = blockIdx.x * 4 + (threadIdx.x >> 6);
    const float4* wr = (const float4*)(w + (size_t)row * K_DIM);
    float4 v[4];
#pragma unroll
    for (int j = 0; j < 4; ++j) v[j] = wr[lane * 4 + j];  // 16 consecutive floats

    float g = 0.f;
#pragma unroll
    for (int j = 0; j < 4; ++j) {
        g = fmaxf(g, fabsf(v[j].x)); g = fmaxf(g, fabsf(v[j].y));
        g = fmaxf(g, fabsf(v[j].z)); g = fmaxf(g, fabsf(v[j].w));
    }
    g = fmaxf(g, __shfl_xor(g, 1, 64));
    g = fmaxf(g, __shfl_xor(g, 2, 64));
    g = fmaxf(g, __shfl_xor(g, 4, 64));
    const float s = __half2float(__float2half(fmaxf(g, 1e-8f)));  // fp16 storage round-trip
    float t = s;
    t += __shfl_xor(t, 8, 64);
    t += __shfl_xor(t, 16, 64);
    t += __shfl_xor(t, 32, 64);
    if (lane == 0) wscale[row] = t * 0.125f;  // mean over 8 groups

    int pk[4];
#pragma unroll
    for (int j = 0; j < 4; ++j) {
        const int b0 = (v[j].x > 0.f) ? 1 : -1;
        const int b1 = (v[j].y > 0.f) ? 1 : -1;
        const int b2 = (v[j].z > 0.f) ? 1 : -1;
        const int b3 = (v[j].w > 0.f) ? 1 : -1;
        pk[j] = (b0 & 255) | ((b1 & 255) << 8) | ((b2 & 255) << 16) | (b3 << 24);
    }
    *(int4*)(wq + (size_t)row * K_DIM + lane * 16) = make_int4(pk[0], pk[1], pk[2], pk[3]);
}

// ---------------- Kernel B: per-token activation quant ----------------
// One wave per token row; lane owns 16 consecutive floats. Full-wave shuffle
// absmax; ONE wave-uniform divide then multiply (was 16 IEEE divides/thread);
// single int4 store per lane.
__global__ __launch_bounds__(256) void quant_x(const float* __restrict__ x,
                                               signed char* __restrict__ xq,
                                               float* __restrict__ xs) {
    const int lane = threadIdx.x & 63;
    const int row  = blockIdx.x * 4 + (threadIdx.x >> 6);
    const float4* xr = (const float4*)(x + (size_t)row * K_DIM);
    float4 v[4];
#pragma unroll
    for (int j = 0; j < 4; ++j) v[j] = xr[lane * 4 + j];

    float am = 0.f;
#pragma unroll
    for (int j = 0; j < 4; ++j) {
        am = fmaxf(am, fabsf(v[j].x)); am = fmaxf(am, fabsf(v[j].y));
        am = fmaxf(am, fabsf(v[j].z)); am = fmaxf(am, fabsf(v[j].w));
    }
#pragma unroll
    for (int off = 32; off >= 1; off >>= 1) am = fmaxf(am, __shfl_xor(am, off, 64));
    const float scale = fmaxf(am, 1e-8f) / 127.f;
    const float inv   = 1.0f / scale;   // wave-uniform, one divide

    int pk[4];
#pragma unroll
    for (int j = 0; j < 4; ++j) {
        const int b0 = (int)fminf(fmaxf(rintf(v[j].x * inv), -128.f), 127.f);
        const int b1 = (int)fminf(fmaxf(rintf(v[j].y * inv), -128.f), 127.f);
        const int b2 = (int)fminf(fmaxf(rintf(v[j].z * inv), -128.f), 127.f);
        const int b3 = (int)fminf(fmaxf(rintf(v[j].w * inv), -128.f), 127.f);
        pk[j] = (b0 & 255) | ((b1 & 255) << 8) | ((b2 & 255) << 16) | (b3 << 24);
    }
    *(int4*)(xq + (size_t)row * K_DIM + lane * 16) = make_int4(pk[0], pk[1], pk[2], pk[3]);
    if (lane == 0) xs[row] = scale;
}

// ---------------- Kernel C: int8 GEMM (m97 structure + XOR-swizzled LDS) ----
// C[m][n] = sum_k A[m][k] * Bw[n][k]. 128x128 tile, BK=128B, 4 waves 2x2,
// each wave 4x4 tiles of 16x16 via mfma_i32_16x16x64_i8.
// LDS layout: phys 16B-chunk = logical chunk ^ (row & 7)  -> each bank quad
// serves 8 lanes per ds_read_b128 (optimal 8 cycles, no serialization).
// Staging stays global_load_lds-compatible: dest is tid*16; the staging
// thread fetches the PERMUTED global column instead.
__global__ __launch_bounds__(256) void gemm_i8(const signed char* __restrict__ A,
                                               const signed char* __restrict__ Bw,
                                               const float* __restrict__ xs,
                                               const float* __restrict__ wscale,
                                               const float* __restrict__ bias,
                                               float* __restrict__ out) {
    __shared__ __align__(16) signed char As[128 * 128];
    __shared__ __align__(16) signed char Bs[128 * 128];

    const int tid  = threadIdx.x;
    const int lane = tid & 63;
    const int wave = tid >> 6;
    const int wm = wave >> 1;   // 0..1
    const int wn = wave & 1;    // 0..1

    // XCD-aware mapping: XCD = bid & 7 (round-robin). Give each XCD its own
    // 32 m-tiles x all 8 n-tiles so an A-tile is fetched into one XCD's L2
    // once and reused for 8 n-tiles (was: 8 different XCDs -> 8x L3 refetch).
    const int bid = blockIdx.x;
    const int xcd = bid & 7;
    const int q   = bid >> 3;           // 0..255 within XCD
    const int mT  = xcd * 32 + (q >> 3);
    const int nT  = q & 7;
    const size_t mBase = (size_t)mT * 128;
    const int    nBase = nT * 128;

    v4i acc[4][4] = {};

    // staging: 256 threads x 16B = 4KB/call = 32 rows of 128B
    const int srow = tid >> 3;                               // 0..31
    const int scol = (((tid & 7) ^ (srow & 7))) * 16;        // swizzled column
    const signed char* Ag = A  + (mBase + srow) * K_DIM + scol;
    const signed char* Bg = Bw + (size_t)(nBase + srow) * K_DIM + scol;

    for (int kt = 0; kt < 8; ++kt) {
        const int koff = kt * 128;
#pragma unroll
        for (int c = 0; c < 4; ++c) {   // row+32c keeps (row&7) -> same scol valid
            async_load16(Ag + (size_t)(c * 32) * K_DIM + koff, As + c * 4096 + tid * 16);
            async_load16(Bg + (size_t)(c * 32) * K_DIM + koff, Bs + c * 4096 + tid * 16);
        }
        __syncthreads();

        const int r16 = lane & 15;
        const int g   = lane >> 4;
        const int x7  = lane & 7;
#pragma unroll
        for (int ks = 0; ks < 2; ++ks) {
            const int co = ((ks * 4 + g) ^ x7) * 16;   // swizzled chunk offset
            v4i af[4], bf[4];
#pragma unroll
            for (int mt = 0; mt < 4; ++mt)
                af[mt] = *(const v4i*)(As + (wm * 64 + mt * 16 + r16) * 128 + co);
#pragma unroll
            for (int nt = 0; nt < 4; ++nt)
                bf[nt] = *(const v4i*)(Bs + (wn * 64 + nt * 16 + r16) * 128 + co);
#pragma unroll
            for (int mt = 0; mt < 4; ++mt)
#pragma unroll
                for (int nt = 0; nt < 4; ++nt)
                    acc[mt][nt] = __builtin_amdgcn_mfma_i32_16x16x64_i8(
                        af[mt], bf[nt], acc[mt][nt], 0, 0, 0);
        }
        __syncthreads();
    }

    // epilogue: C/D layout col = lane&15, row = (lane>>4)*4 + reg
    const int cc = lane & 15;
    const int rq = (lane >> 4) * 4;
    float xsr[4][4];
#pragma unroll
    for (int mt = 0; mt < 4; ++mt)
#pragma unroll
        for (int i = 0; i < 4; ++i)
            xsr[mt][i] = xs[mBase + wm * 64 + mt * 16 + rq + i];

#pragma unroll
    for (int nt = 0; nt < 4; ++nt) {
        const int col  = nBase + wn * 64 + nt * 16 + cc;
        const float wsc = wscale[col];
        const float bb  = bias[col];
#pragma unroll
        for (int mt = 0; mt < 4; ++mt) {
#pragma unroll
            for (int i = 0; i < 4; ++i) {
                const size_t row = mBase + wm * 64 + mt * 16 + rq + i;
                out[row * N_DIM + col] = ((float)acc[mt][nt][i] * xsr[mt][i]) * wsc + bb;
            }
        }
    }
}

extern "C" void kernel_launch(void* const* d_in, const int* in_sizes, int n_in,
                              void* d_out, int out_size, void* d_ws, size_t ws_size,
                              hipStream_t stream) {
    const float* x    = (const float*)d_in[0];
    const float* w    = (const float*)d_in[1];
    const float* bias = (const float*)d_in[2];
    float* out = (float*)d_out;

    const int BT = in_sizes[0] / K_DIM;  // 32768 tokens

    // workspace carve
    char* ws = (char*)d_ws;
    signed char* xq     = (signed char*)ws;                                          // BT*1024 B
    float*       xs     = (float*)(ws + (size_t)BT * K_DIM);                         // BT*4 B
    signed char* wq     = (signed char*)(ws + (size_t)BT * K_DIM + (size_t)BT * 4);  // 1 MB
    float*       wscale = (float*)((char*)wq + (size_t)N_DIM * K_DIM);               // 4 KB

    prep_w<<<N_DIM / 4, 256, 0, stream>>>(w, wq, wscale);
    quant_x<<<BT / 4, 256, 0, stream>>>(x, xq, xs);
    gemm_i8<<<(BT / 128) * (N_DIM / 128), 256, 0, stream>>>(xq, wq, xs, wscale, bias, out);
}